// Round 5
// baseline (1014.189 us; speedup 1.0000x reference)
//
#include <hip/hip_runtime.h>
#include <hip/hip_fp16.h>

#define IN_F 128
#define H_F 64
#define C_F 16
#define BUCKET 256          // dst-nodes per bucket
#define BSH 8               // log2(BUCKET)
#define MAXB 512            // scan/hist capacity (>= nBuckets)
#define EPB 8192            // edges per k_bin block

// ---------------- degree histograms ----------------
__global__ void k_degrees(const int* __restrict__ src, const int* __restrict__ dst,
                          int* __restrict__ degi_out, int* __restrict__ degi_in, int E) {
    int e = blockIdx.x * 256 + threadIdx.x;
    if (e < E) {
        atomicAdd(&degi_out[src[e]], 1);
        atomicAdd(&degi_in[dst[e]], 1);
    }
}

// ---------------- norms ----------------
__global__ void k_norms(const int* __restrict__ degi_out, const int* __restrict__ degi_in,
                        float* __restrict__ norm_out, float* __restrict__ norm_in, int N) {
    int n = blockIdx.x * 256 + threadIdx.x;
    if (n < N) {
        norm_out[n] = 1.0f / sqrtf((float)max(degi_out[n], 1));
        norm_in[n]  = 1.0f / sqrtf((float)max(degi_in[n], 1));
    }
}

// ---------------- per-bucket edge counts (sum of degi_in over 256 nodes) ----------------
__global__ __launch_bounds__(BUCKET) void k_bucketcnt(const int* __restrict__ degi_in,
                                                      int* __restrict__ bucketCnt, int N) {
    __shared__ int s[BUCKET];
    int n = blockIdx.x * BUCKET + threadIdx.x;
    s[threadIdx.x] = (n < N) ? degi_in[n] : 0;
    __syncthreads();
    for (int off = BUCKET / 2; off; off >>= 1) {
        if (threadIdx.x < off) s[threadIdx.x] += s[threadIdx.x + off];
        __syncthreads();
    }
    if (threadIdx.x == 0) bucketCnt[blockIdx.x] = s[0];
}

// ---------------- exclusive scan of bucket counts (single block) ----------------
__global__ __launch_bounds__(MAXB) void k_bucketscan(const int* __restrict__ bucketCnt,
                                                     int* __restrict__ bucketBase,
                                                     int* __restrict__ gCursor, int nb, int E) {
    __shared__ int s[MAXB];
    int t = threadIdx.x;
    int v = (t < nb) ? bucketCnt[t] : 0;
    s[t] = v;
    __syncthreads();
    for (int off = 1; off < MAXB; off <<= 1) {
        int x = (t >= off) ? s[t - off] : 0;
        __syncthreads();
        s[t] += x;
        __syncthreads();
    }
    if (t < nb) {
        int excl = s[t] - v;
        bucketBase[t] = excl;
        gCursor[t]    = excl;
        if (t == nb - 1) bucketBase[nb] = E;
    }
}

// ---------------- bin edges by bucket (grouped writes) + wsum[s] += norm_in[d] ----------
// code = (dlocal << 17) | src   (src < 2^17, dlocal < 256)
__global__ __launch_bounds__(256) void k_bin(const int* __restrict__ src,
                                             const int* __restrict__ dst,
                                             const float* __restrict__ norm_in,
                                             float* __restrict__ wsum,
                                             int* __restrict__ gCursor,
                                             unsigned int* __restrict__ binned,
                                             int E, int nb) {
    __shared__ int hist[MAXB];
    __shared__ int base[MAXB];
    __shared__ int cur[MAXB];
    const int tid = threadIdx.x;
    const int start = blockIdx.x * EPB;
    for (int i = tid; i < MAXB; i += 256) { hist[i] = 0; cur[i] = 0; }
    __syncthreads();
#pragma unroll 4
    for (int k = 0; k < EPB / 256; ++k) {
        int e = start + (k << 8) + tid;
        if (e < E) atomicAdd(&hist[dst[e] >> BSH], 1);
    }
    __syncthreads();
    for (int b = tid; b < nb; b += 256)
        if (hist[b]) base[b] = atomicAdd(&gCursor[b], hist[b]);
    __syncthreads();
    for (int k = 0; k < EPB / 256; ++k) {
        int e = start + (k << 8) + tid;
        if (e < E) {
            int s = src[e], d = dst[e];
            int b = d >> BSH;
            int p = base[b] + atomicAdd(&cur[b], 1);
            binned[p] = ((unsigned)(d & (BUCKET - 1)) << 17) | (unsigned)s;
            atomicAdd(&wsum[s], norm_in[d]);
        }
    }
}

// ---------------- layer 1 GEMM: X1h = fp16((in_feat @ W1) * norm_out), [N,64] ----------
__global__ __launch_bounds__(256) void k_gemm1(const float* __restrict__ in_feat,
                                               const float* __restrict__ W1,
                                               const float* __restrict__ norm_out,
                                               __half* __restrict__ X1h, int N) {
    __shared__ float Wl[IN_F][H_F];       // 32 KB
    __shared__ float Al[64][IN_F + 4];    // 33 KB
    const int t = threadIdx.x;
    const int base = blockIdx.x * 64;

    for (int i = t; i < IN_F * H_F / 4; i += 256)
        ((float4*)&Wl[0][0])[i] = ((const float4*)W1)[i];
    for (int i = t; i < 64 * IN_F / 4; i += 256) {
        int n = i >> 5;
        int k4 = i & 31;
        int gn = base + n;
        float4 v = make_float4(0.f, 0.f, 0.f, 0.f);
        if (gn < N) v = ((const float4*)(in_feat + (size_t)gn * IN_F))[k4];
        *(float4*)&Al[n][k4 * 4] = v;
    }
    __syncthreads();

    const int c4 = (t & 15) * 4;
    const int r4 = (t >> 4) * 4;
    float acc[4][4] = {};
#pragma unroll 4
    for (int k = 0; k < IN_F; k += 4) {
        float4 w0 = *(const float4*)&Wl[k + 0][c4];
        float4 w1 = *(const float4*)&Wl[k + 1][c4];
        float4 w2 = *(const float4*)&Wl[k + 2][c4];
        float4 w3 = *(const float4*)&Wl[k + 3][c4];
        const float* wp0 = (const float*)&w0;
        const float* wp1 = (const float*)&w1;
        const float* wp2 = (const float*)&w2;
        const float* wp3 = (const float*)&w3;
#pragma unroll
        for (int i = 0; i < 4; ++i) {
            float4 a = *(const float4*)&Al[r4 + i][k];
#pragma unroll
            for (int jj = 0; jj < 4; ++jj)
                acc[i][jj] = fmaf(a.x, wp0[jj],
                             fmaf(a.y, wp1[jj],
                             fmaf(a.z, wp2[jj],
                             fmaf(a.w, wp3[jj], acc[i][jj]))));
        }
    }
#pragma unroll
    for (int i = 0; i < 4; ++i) {
        int n = base + r4 + i;
        if (n < N) {
            float no = norm_out[n];
            __half2 p0 = __floats2half2_rn(acc[i][0] * no, acc[i][1] * no);
            __half2 p1 = __floats2half2_rn(acc[i][2] * no, acc[i][3] * no);
            __half2* dp = (__half2*)&X1h[(size_t)n * H_F + c4];
            dp[0] = p0; dp[1] = p1;
        }
    }
}

// ---- fused aggregation: per-bucket LDS accumulate + relu/bias + weighted colsum -------
// block = bucket (256 nodes). acc[256][64] fp32 in LDS via ds_add_f32.
__global__ __launch_bounds__(256) void k_agg(const __half* __restrict__ X1h,
                                             const unsigned int* __restrict__ binned,
                                             const int* __restrict__ bucketBase,
                                             const float* __restrict__ norm_in,
                                             const float* __restrict__ norm_out,
                                             const float* __restrict__ wsum,
                                             const float* __restrict__ b1,
                                             float* __restrict__ partials, int N) {
    __shared__ float acc[BUCKET * H_F];   // 64 KB
    __shared__ float hl[4][64];
    const int tid = threadIdx.x, lane = tid & 63, wave = tid >> 6;

    for (int i = tid; i < BUCKET * H_F / 4; i += 256)
        ((float4*)acc)[i] = make_float4(0.f, 0.f, 0.f, 0.f);
    __syncthreads();

    const int base = bucketBase[blockIdx.x];
    const int cnt  = bucketBase[blockIdx.x + 1] - base;

    for (int c0 = wave * 64; c0 < cnt; c0 += 256) {
        int m = cnt - c0;
        if (m > 64) m = 64;
        unsigned code = 0;
        if (lane < m) code = binned[base + c0 + lane];
        if (m == 64) {
#pragma unroll 8
            for (int it = 0; it < 64; ++it) {
                unsigned bc = __shfl(code, it);
                int s  = (int)(bc & 0x1FFFFu);
                int dl = (int)(bc >> 17);
                float v = __half2float(X1h[(size_t)s * H_F + lane]);
                atomicAdd(&acc[dl * H_F + lane], v);
            }
        } else {
            for (int it = 0; it < m; ++it) {
                unsigned bc = __shfl(code, it);
                int s  = (int)(bc & 0x1FFFFu);
                int dl = (int)(bc >> 17);
                float v = __half2float(X1h[(size_t)s * H_F + lane]);
                atomicAdd(&acc[dl * H_F + lane], v);
            }
        }
    }
    __syncthreads();

    // epilogue: wave w handles nodes w*64 .. w*64+63; lane = feature
    const float bj = b1[lane];
    float hacc = 0.0f;
    for (int k = 0; k < 64; ++k) {
        int nl = wave * 64 + k;
        int gn = blockIdx.x * BUCKET + nl;
        if (gn < N) {
            float ni = norm_in[gn];
            float w  = norm_out[gn] * wsum[gn];
            float v  = acc[nl * H_F + lane] * ni + bj;
            hacc = fmaf(v > 0.0f ? v : 0.0f, w, hacc);
        }
    }
    hl[wave][lane] = hacc;
    __syncthreads();
    if (wave == 0)
        partials[(size_t)blockIdx.x * 64 + lane] =
            (hl[0][lane] + hl[1][lane]) + (hl[2][lane] + hl[3][lane]);
}

// ---------------- final: hsum (f64) -> out = hsum@W2/N + b2 ----------------
__global__ __launch_bounds__(256) void k_final(const float* __restrict__ partials,
                                               const float* __restrict__ W2,
                                               const float* __restrict__ b2,
                                               float* __restrict__ out, int nb, int N) {
    __shared__ double hs[4][64];
    const int sub = threadIdx.x >> 6;   // 0..3
    const int j   = threadIdx.x & 63;
    double s = 0.0;
    for (int p = sub; p < nb; p += 4)
        s += (double)partials[(size_t)p * 64 + j];
    hs[sub][j] = s;
    __syncthreads();
    if (threadIdx.x < C_F) {
        int c = threadIdx.x;
        double o = 0.0;
        for (int k = 0; k < 64; ++k) {
            double hk = hs[0][k] + hs[1][k] + hs[2][k] + hs[3][k];
            o += hk * (double)W2[k * C_F + c];
        }
        out[c] = (float)(o / (double)N + (double)b2[c]);
    }
}

extern "C" void kernel_launch(void* const* d_in, const int* in_sizes, int n_in,
                              void* d_out, int out_size, void* d_ws, size_t ws_size,
                              hipStream_t stream) {
    const float* in_feat = (const float*)d_in[0];
    const int*   src     = (const int*)d_in[1];
    const int*   dst     = (const int*)d_in[2];
    const float* W1      = (const float*)d_in[3];
    const float* b1      = (const float*)d_in[4];
    const float* W2      = (const float*)d_in[5];
    const float* b2      = (const float*)d_in[6];
    float* out = (float*)d_out;

    const int N = in_sizes[0] / IN_F;           // 100000
    const int E = in_sizes[1];                  // 1600000
    const int nb = (N + BUCKET - 1) / BUCKET;   // 391 (<= MAXB)

    // ---- workspace layout (4B units) ----
    unsigned int* binned = (unsigned int*)d_ws;          // E
    int*   degi_out  = (int*)(binned + E);               // N
    int*   degi_in   = degi_out + N;                     // N
    float* wsum      = (float*)(degi_in + N);            // N (zeroed with degrees)
    float* norm_out  = wsum + N;                         // N
    float* norm_in   = norm_out + N;                     // N
    int*   bucketCnt = (int*)(norm_in + N);              // MAXB
    int*   bucketBase= bucketCnt + MAXB;                 // MAXB+1
    int*   gCursor   = bucketBase + MAXB + 1;            // MAXB (+3 pad)
    __half* X1h      = (__half*)(gCursor + MAXB + 3);    // 64N halves
    float* partials  = (float*)(X1h + 64 * (size_t)N);   // nb*64

    // degrees + wsum are read-before-write (contiguous 3N)
    hipMemsetAsync(degi_out, 0, 3 * (size_t)N * sizeof(int), stream);

    k_degrees<<<(E + 255) / 256, 256, 0, stream>>>(src, dst, degi_out, degi_in, E);
    k_norms  <<<(N + 255) / 256, 256, 0, stream>>>(degi_out, degi_in, norm_out, norm_in, N);

    k_bucketcnt <<<nb, BUCKET, 0, stream>>>(degi_in, bucketCnt, N);
    k_bucketscan<<<1, MAXB, 0, stream>>>(bucketCnt, bucketBase, gCursor, nb, E);

    k_bin<<<(E + EPB - 1) / EPB, 256, 0, stream>>>(src, dst, norm_in, wsum, gCursor,
                                                   binned, E, nb);

    k_gemm1<<<(N + 63) / 64, 256, 0, stream>>>(in_feat, W1, norm_out, X1h, N);

    k_agg<<<nb, 256, 0, stream>>>(X1h, binned, bucketBase, norm_in, norm_out,
                                  wsum, b1, partials, N);

    k_final<<<1, 256, 0, stream>>>(partials, W2, b2, out, nb, N);
}